// Round 12
// baseline (276.999 us; speedup 1.0000x reference)
//
#include <hip/hip_runtime.h>
#include <cstdint>
#include <cstddef>

typedef unsigned short u16;
typedef unsigned int   u32;
typedef __bf16 bf16x8 __attribute__((ext_vector_type(8)));
typedef float  f32x4  __attribute__((ext_vector_type(4)));

#define D_MODEL 1024
#define SEQ     2048
#define NTOK    4096   // B*S
#define NHEAD   16
#define DK      64

// hardware exp2 (v_exp_f32)
__device__ __forceinline__ float fast_exp2(float x) {
  return __builtin_amdgcn_exp2f(x);
}

// fp32 -> bf16 round-to-nearest-even
__device__ __forceinline__ u16 f2bf(float f) {
  u32 u = __builtin_bit_cast(u32, f);
  u += 0x7fffu + ((u >> 16) & 1u);
  return (u16)(u >> 16);
}

// async global->LDS, 16B per lane (dest must be wave-uniform base + lane*16)
__device__ __forceinline__ void gload16(const u16* g, u16* l) {
  __builtin_amdgcn_global_load_lds(
      (__attribute__((address_space(1))) void*)(uintptr_t)g,
      (__attribute__((address_space(3))) void*)l,
      16, 0, 0);
}

// ---------------------------------------------------------------------------
// Kernel 1: prep = mask scan (blocks 0-1) + weight fp32->bf16 (blocks 2..)
// ---------------------------------------------------------------------------
__global__ __launch_bounds__(256) void prep(
    const int* __restrict__ mask, const float* __restrict__ wq,
    const float* __restrict__ wk, const float* __restrict__ wv,
    const float* __restrict__ wo, u16* __restrict__ wb,
    int* __restrict__ idx, int* __restrict__ cnt) {
  const int t = threadIdx.x;
  if (blockIdx.x < 2) {
    // ---- per-batch mask compaction scan ----
    const int b = blockIdx.x;
    const int lane = t & 63, w = t >> 6;
    __shared__ int sW[4];
    __shared__ int sTot;
    int m8[8];
    const int base = b * SEQ + t * 8;
    int tot = 0;
#pragma unroll
    for (int i = 0; i < 8; ++i) {
      m8[i] = (mask[base + i] != 0);
      tot += m8[i];
    }
    int v = tot;  // wave inclusive scan
#pragma unroll
    for (int d = 1; d < 64; d <<= 1) {
      int u = __shfl_up(v, d);
      if (lane >= d) v += u;
    }
    if (lane == 63) sW[w] = v;
    __syncthreads();
    if (t == 0) {
      int run = 0;
#pragma unroll
      for (int i = 0; i < 4; ++i) { int tmp = sW[i]; sW[i] = run; run += tmp; }
      sTot = run;
    }
    __syncthreads();
    int pos = v - tot + sW[w];
#pragma unroll
    for (int i = 0; i < 8; ++i)
      if (m8[i]) idx[b * SEQ + pos++] = t * 8 + i;
    const int cn = sTot;
    if (t == 0) cnt[b] = cn;
    for (int j = cn + t; j < SEQ; j += 256) idx[b * SEQ + j] = 0;
  } else {
    // ---- weights fp32 -> bf16 (4 x 1M) ----
    const int total = 1 << 20;  // float4 chunks
    const int stride = (gridDim.x - 2) * 256;
    for (int cid = (blockIdx.x - 2) * 256 + t; cid < total; cid += stride) {
      int which = cid >> 18;
      int off = cid & ((1 << 18) - 1);
      const float* src =
          which == 0 ? wq : (which == 1 ? wk : (which == 2 ? wv : wo));
      u16* dst = wb + ((size_t)which << 20);
      float4 f = ((const float4*)src)[off];
      ushort4 u;
      u.x = f2bf(f.x); u.y = f2bf(f.y); u.z = f2bf(f.z); u.w = f2bf(f.w);
      ((ushort4*)dst)[off] = u;
    }
  }
}

// ---------------------------------------------------------------------------
// Kernel 2: QKV projections, fp32 A read directly as per-lane MFMA fragments
// (no LDS for A, no staging convert).  C = A*B^T + bias, bf16 out.
// 128x128 tile, BK=64, grid (mtile=32, ntile=8, z=3): flat%8 = mtile%8 ->
// XCD L2 reuse.  Single-barrier loop: sB double-buffered via gload16 issued
// post-barrier; A fragments prefetched one iter ahead in registers (pa freed
// by the in-reg convert, reloaded immediately).  Rotated B k-slots ->
// conflict-free ds_read_b128.  A frag loads: 16 rows x 64B lines, coalesced;
// 2 waves sharing rows dedup in L1/L2.
// z==0: Q scaled by 0.125*log2(e).  z==2: V transposed [b][h][d][s].
// ---------------------------------------------------------------------------
__global__ __launch_bounds__(256, 2) void gemm_qkv(
    const float* __restrict__ Aq, const float* __restrict__ Ak,
    const float* __restrict__ Av, const u16* __restrict__ Bw,
    const float* __restrict__ b0, const float* __restrict__ b1,
    const float* __restrict__ b2, u16* __restrict__ Cout) {
  __shared__ __align__(16) u16 smem[128 * 136];  // sB dbuf 2x16KB; epi sC 34.8KB

  const int t = threadIdx.x;
  const int z = blockIdx.z;
  const float* Ap = (z == 0) ? Aq : ((z == 1) ? Ak : Av);
  const u16* Bp = Bw + ((size_t)z << 20);
  const float* bias = (z == 0) ? b0 : ((z == 1) ? b1 : b2);
  const float scl = (z == 0) ? 0.18033688011f : 1.0f;

  const int m0 = blockIdx.x * 128, n0 = blockIdx.y * 128;  // XCD swizzle
  const int lane = t & 63, wv = t >> 6;
  const int wm = (wv >> 1) * 64, wn = (wv & 1) * 64;
  const int c = lane & 15, qd = lane >> 4;

  // B staging: chunk cc = t + 256j -> row = t>>3 + 32j, phys slot t&7,
  // source k-slot rotated by row (32j = 0 mod 8 -> j-invariant)
  const int brow = t >> 3;
  const int boff = (((t & 7) - brow) & 7) * 8;
  const u16* gaB = Bp + (size_t)(n0 + brow) * D_MODEL + boff;

  // A fragment base: lane covers row m0+wm+i*16+c, k = kb + s*32 + qd*8
  const float* gA = Ap + (size_t)(m0 + wm + c) * D_MODEL + qd * 8;

  // prologue: A(0) frags -> pa regs, B(0) -> sB0
  float4 pa[8][2];  // f = i*2+s
#pragma unroll
  for (int f = 0; f < 8; ++f) {
    const float* p = gA + (f >> 1) * (16 * D_MODEL) + (f & 1) * 32;
    pa[f][0] = *(const float4*)p;
    pa[f][1] = *(const float4*)(p + 4);
  }
#pragma unroll
  for (int j = 0; j < 4; ++j)
    gload16(gaB + (size_t)(32 * j) * D_MODEL, smem + (t + 256 * j) * 8);

  f32x4 acc[4][4] = {};

  for (int kbi = 0; kbi < 16; ++kbi) {
    const int cur = kbi & 1;
    __syncthreads();  // drains B(i)->sB[cur] + pa=A(i); sB[1-cur] free
    // issue B(i+1) immediately (max cover)
    if (kbi + 1 < 16) {
      u16* sBn = smem + (1 - cur) * 8192;
#pragma unroll
      for (int j = 0; j < 4; ++j)
        gload16(gaB + (kbi + 1) * 64 + (size_t)(32 * j) * D_MODEL,
                sBn + (t + 256 * j) * 8);
    }
    // convert pa -> af (pa dies), then reload pa = A(i+1)
    bf16x8 af[8];
#pragma unroll
    for (int f = 0; f < 8; ++f) {
      u32 w0 = (u32)f2bf(pa[f][0].x) | ((u32)f2bf(pa[f][0].y) << 16);
      u32 w1 = (u32)f2bf(pa[f][0].z) | ((u32)f2bf(pa[f][0].w) << 16);
      u32 w2 = (u32)f2bf(pa[f][1].x) | ((u32)f2bf(pa[f][1].y) << 16);
      u32 w3 = (u32)f2bf(pa[f][1].z) | ((u32)f2bf(pa[f][1].w) << 16);
      uint4 u4 = {w0, w1, w2, w3};
      af[f] = __builtin_bit_cast(bf16x8, u4);
    }
    if (kbi + 1 < 16) {
      const int kb2 = (kbi + 1) * 64;
#pragma unroll
      for (int f = 0; f < 8; ++f) {
        const float* p = gA + kb2 + (f >> 1) * (16 * D_MODEL) + (f & 1) * 32;
        pa[f][0] = *(const float4*)p;
        pa[f][1] = *(const float4*)(p + 4);
      }
    }
    const u16* sB = smem + cur * 8192;
#pragma unroll
    for (int s = 0; s < 2; ++s) {
      const int bo = ((s * 4 + qd + wn + c) & 7) * 8;  // rotated k-slot
      bf16x8 bfr[4];
#pragma unroll
      for (int j = 0; j < 4; ++j)
        bfr[j] = *(const bf16x8*)&sB[(wn + j * 16 + c) * 64 + bo];
#pragma unroll
      for (int i = 0; i < 4; ++i)
#pragma unroll
        for (int j = 0; j < 4; ++j)
          acc[i][j] = __builtin_amdgcn_mfma_f32_16x16x32_bf16(
              af[i * 2 + s], bfr[j], acc[i][j], 0, 0, 0);
    }
  }
  __syncthreads();  // last MFMA reads done before smem reuse as sC

  u16* sC = smem;  // stride 136
  if (z == 2) {
#pragma unroll
    for (int j = 0; j < 4; ++j) {
      const int col = wn + j * 16 + c;
      const float bv = bias[n0 + col];
#pragma unroll
      for (int i = 0; i < 4; ++i)
#pragma unroll
        for (int r = 0; r < 4; ++r)
          sC[col * 136 + wm + i * 16 + qd * 4 + r] = f2bf(acc[i][j][r] + bv);
    }
    __syncthreads();
    u16* VT = Cout + ((size_t)2 << 22);
    const int bb = m0 >> 11, s0 = m0 & 2047;
    const int sidx = (t & 15) * 8;
#pragma unroll
    for (int outer = 0; outer < 8; ++outer) {
      const int vrow = outer * 16 + (t >> 4);
      const int col = n0 + vrow;
      const int hh = col >> 6, dd = col & 63;
      uint4 val = *(const uint4*)&sC[vrow * 136 + sidx];
      *(uint4*)&VT[((size_t)((bb * NHEAD + hh) * DK + dd)) * SEQ + s0 + sidx] =
          val;
    }
  } else {
#pragma unroll
    for (int j = 0; j < 4; ++j) {
      const int col = wn + j * 16 + c;
      const float bv = bias[n0 + col];
#pragma unroll
      for (int i = 0; i < 4; ++i)
#pragma unroll
        for (int r = 0; r < 4; ++r)
          sC[(wm + i * 16 + qd * 4 + r) * 136 + col] =
              f2bf((acc[i][j][r] + bv) * scl);
    }
    __syncthreads();
    u16* outp = Cout + ((size_t)z << 22);
    const int cidx = (t & 15) * 8;
#pragma unroll
    for (int outer = 0; outer < 8; ++outer) {
      const int lrow = outer * 16 + (t >> 4);
      uint4 val = *(const uint4*)&sC[lrow * 136 + cidx];
      *(uint4*)&outp[(size_t)(m0 + lrow) * D_MODEL + n0 + cidx] = val;
    }
  }
}

// ---------------------------------------------------------------------------
// Kernel 3: compact V^T along s: VTc[row][j] = VT[row][idx[b][j]], j<cnt[b].
// ---------------------------------------------------------------------------
__global__ __launch_bounds__(256) void vtc_gather(const u16* __restrict__ VT,
                                                  const int* __restrict__ idx,
                                                  const int* __restrict__ cnt,
                                                  u16* __restrict__ VTc) {
  const int row = blockIdx.x;  // (b*16+h)*64+d in [0,2048)
  const int b = row >> 10;
  const int cn = cnt[b];
  const u16* src = VT + (size_t)row * SEQ;
  u16* dst = VTc + (size_t)row * SEQ;
  const int* ib = idx + b * SEQ;
  for (int j = threadIdx.x; j < cn; j += 256) dst[j] = src[ib[j]];
}

// ---------------------------------------------------------------------------
// Kernel 4: flash attention over COMPACTED live keys.  S^T orientation,
// fixed-max softmax (m=16, exp2 domain).  Split-K x2, pipelined prefetch.
// ---------------------------------------------------------------------------
__global__ __launch_bounds__(256) void mha_attn(
    const u16* __restrict__ QKVb, const u16* __restrict__ VTc,
    const int* __restrict__ idx, const int* __restrict__ cnt,
    u16* __restrict__ Opart, float* __restrict__ ml) {
  __shared__ __align__(16) u16 sK[64 * 72];
  __shared__ __align__(16) u16 sVt[64 * 72];   // [d][key]
  __shared__ __align__(16) u16 sP[128 * 72];   // [q][key] = P^T rows

  const int t = threadIdx.x, lane = t & 63, wq = t >> 6;
  const int c = lane & 15, qd = lane >> 4;
  const int qb = blockIdx.x, h = blockIdx.y;
  const int b = blockIdx.z & 1, ck = blockIdx.z >> 1;

  const int cn = cnt[b];
  const int nb = (cn + 63) >> 6;
  const int half = (nb + 1) >> 1;
  const int kstart = ck ? half : 0;
  const int kend = ck ? nb : half;

  const u16* Qg = QKVb;
  const u16* Kg = QKVb + ((size_t)4 << 20);
  const u16* VTch = VTc + ((size_t)((b * NHEAD + h) * DK)) * SEQ;
  const int rowbase = b * SEQ;
  const int colbase = h * DK;

  // ---- Q B-fragments direct from global (lane n=q=c, k=qd*8+j) ----
  bf16x8 aq[2][2];
#pragma unroll
  for (int qt = 0; qt < 2; ++qt) {
    const u16* g = Qg +
                   (size_t)(rowbase + qb * 128 + wq * 32 + qt * 16 + c) * D_MODEL +
                   colbase + qd * 8;
    aq[qt][0] = *(const bf16x8*)g;
    aq[qt][1] = *(const bf16x8*)(g + 32);
  }

  float l[2] = {0.f, 0.f};
  f32x4 o[2][4] = {};
  const float MADD = -1.4426950e9f;  // NEG_INF * log2(e)
  const float MFIX = 16.0f;          // fixed softmax max (exp2 domain)

  const int r0s = t >> 2, offs = (t & 3) * 16;
  const u16* gvb = VTch + (size_t)r0s * SEQ + offs;
  const int* idxb = idx + b * SEQ + r0s;

  uint4 k0, k1, v0, v1;
  int sNext2 = 0;
  if (kstart < kend) {
    const int s0i = idxb[kstart * 64];
    const u16* gk = Kg + (size_t)(rowbase + s0i) * D_MODEL + colbase + offs;
    const u16* gv = gvb + kstart * 64;
    k0 = *(const uint4*)gk;
    k1 = *(const uint4*)(gk + 8);
    v0 = *(const uint4*)gv;
    v1 = *(const uint4*)(gv + 8);
    if (kstart + 1 < kend) sNext2 = idxb[(kstart + 1) * 64];
  }

  for (int kbi = kstart; kbi < kend; ++kbi) {
    __syncthreads();  // previous iteration's sK/sVt reads complete
    *(uint4*)&sK[r0s * 72 + offs] = k0;
    *(uint4*)&sK[r0s * 72 + offs + 8] = k1;
    *(uint4*)&sVt[r0s * 72 + offs] = v0;
    *(uint4*)&sVt[r0s * 72 + offs + 8] = v1;
    __syncthreads();
    // prefetch next: K via idx loaded a full iteration earlier
    if (kbi + 1 < kend) {
      const u16* gk = Kg + (size_t)(rowbase + sNext2) * D_MODEL + colbase + offs;
      const u16* gv = gvb + (kbi + 1) * 64;
      k0 = *(const uint4*)gk;
      k1 = *(const uint4*)(gk + 8);
      v0 = *(const uint4*)gv;
      v1 = *(const uint4*)(gv + 8);
    }
    if (kbi + 2 < kend) sNext2 = idxb[(kbi + 2) * 64];

    // ---- S^T = K Q^T (+ pad mask on last partial block) ----
    const bool full = ((kbi + 1) << 6) <= cn;
    f32x4 st[2][4];
#pragma unroll
    for (int tt = 0; tt < 4; ++tt) {
      bf16x8 ak0 = *(const bf16x8*)&sK[(tt * 16 + c) * 72 + qd * 8];
      bf16x8 ak1 = *(const bf16x8*)&sK[(tt * 16 + c) * 72 + qd * 8 + 32];
      f32x4 cin;
      if (full) {
        cin = f32x4{0.f, 0.f, 0.f, 0.f};
      } else {
        const int jb = (kbi << 6) + tt * 16 + qd * 4;
        cin = f32x4{jb + 0 < cn ? 0.f : MADD, jb + 1 < cn ? 0.f : MADD,
                    jb + 2 < cn ? 0.f : MADD, jb + 3 < cn ? 0.f : MADD};
      }
#pragma unroll
      for (int qt = 0; qt < 2; ++qt) {
        f32x4 a =
            __builtin_amdgcn_mfma_f32_16x16x32_bf16(ak0, aq[qt][0], cin, 0, 0, 0);
        a = __builtin_amdgcn_mfma_f32_16x16x32_bf16(ak1, aq[qt][1], a, 0, 0, 0);
        st[qt][tt] = a;
      }
    }

    // ---- softmax numerator: p = exp2(s - MFIX) ----
#pragma unroll
    for (int qt = 0; qt < 2; ++qt) {
      float sum = 0.f;
      const int prow = (wq * 32 + qt * 16 + c) * 72;
#pragma unroll
      for (int tt = 0; tt < 4; ++tt) {
        u32 pk[2];
#pragma unroll
        for (int pr = 0; pr < 2; ++pr) {
          u32 p0 = __builtin_bit_cast(u32, fast_exp2(st[qt][tt][2 * pr] - MFIX));
          u32 p1 =
              __builtin_bit_cast(u32, fast_exp2(st[qt][tt][2 * pr + 1] - MFIX));
          u32 hi1 = p1 & 0xffff0000u;
          pk[pr] = (p0 >> 16) | hi1;
          sum += __builtin_bit_cast(float, p0 & 0xffff0000u);
          sum += __builtin_bit_cast(float, hi1);
        }
        uint2 pv2 = {pk[0], pk[1]};
        *(uint2*)&sP[prow + tt * 16 + qd * 4] = pv2;  // ds_write_b64
      }
      l[qt] += sum;
    }

    // ---- O^T += V^T P^T ----
    bf16x8 bp[2][2];
#pragma unroll
    for (int qt = 0; qt < 2; ++qt) {
      const int prow = (wq * 32 + qt * 16 + c) * 72;
      bp[qt][0] = *(const bf16x8*)&sP[prow + qd * 8];
      bp[qt][1] = *(const bf16x8*)&sP[prow + qd * 8 + 32];
    }
#pragma unroll
    for (int dt = 0; dt < 4; ++dt) {
      bf16x8 av0 = *(const bf16x8*)&sVt[(dt * 16 + c) * 72 + qd * 8];
      bf16x8 av1 = *(const bf16x8*)&sVt[(dt * 16 + c) * 72 + qd * 8 + 32];
#pragma unroll
      for (int qt = 0; qt < 2; ++qt) {
        o[qt][dt] =
            __builtin_amdgcn_mfma_f32_16x16x32_bf16(av0, bp[qt][0], o[qt][dt], 0, 0, 0);
        o[qt][dt] =
            __builtin_amdgcn_mfma_f32_16x16x32_bf16(av1, bp[qt][1], o[qt][dt], 0, 0, 0);
      }
    }
  }

  // ---- epilogue ----
  const size_t obase =
      (size_t)ck * 4194304 + ((size_t)((b * NHEAD + h) * SEQ) + qb * 128) * 64;
  const int mlbase = ((ck * 2 + b) * NHEAD + h) * SEQ + qb * 128;
#pragma unroll
  for (int qt = 0; qt < 2; ++qt) {
    float ls = l[qt];
    ls += __shfl_xor(ls, 16);
    ls += __shfl_xor(ls, 32);
    const float inv = (ls != 0.f) ? 1.0f / ls : 0.f;
    const int q = wq * 32 + qt * 16 + c;
#pragma unroll
    for (int dt = 0; dt < 4; ++dt) {
      u32 lo = (u32)f2bf(o[qt][dt][0] * inv) |
               ((u32)f2bf(o[qt][dt][1] * inv) << 16);
      u32 hi = (u32)f2bf(o[qt][dt][2] * inv) |
               ((u32)f2bf(o[qt][dt][3] * inv) << 16);
      uint2 ov = {lo, hi};
      *(uint2*)&Opart[obase + (size_t)q * 64 + dt * 16 + qd * 4] = ov;
    }
    if (qd == 0) ml[mlbase + q] = ls;
  }
}

// ---------------------------------------------------------------------------
// Kernel 5: combine the two key-chunk partials -> ctx bf16
// ---------------------------------------------------------------------------
__global__ __launch_bounds__(256) void mha_combine(
    const u16* __restrict__ Opart, const float* __restrict__ ml,
    u16* __restrict__ ctx) {
  const int tid = blockIdx.x * 256 + threadIdx.x;  // 524288 = 65536 rows x 8
  const int row = tid >> 3, d0 = (tid & 7) * 8;
  const int b = row >> 15, h = (row >> 11) & 15, q = row & 2047;
  float l1 = ml[row];
  float l2 = ml[65536 + row];
  float inv = 1.0f / (l1 + l2);
  float w1 = l1 * inv, w2 = l2 * inv;
  const size_t o1 = (size_t)row * 64 + d0;
  uint4 pa = *(const uint4*)(Opart + o1);
  uint4 pb = *(const uint4*)(Opart + 4194304 + o1);
  u32 wa[4] = {pa.x, pa.y, pa.z, pa.w};
  u32 wb[4] = {pb.x, pb.y, pb.z, pb.w};
  u32 out[4];
#pragma unroll
  for (int j = 0; j < 4; ++j) {
    float alo = __builtin_bit_cast(float, wa[j] << 16);
    float ahi = __builtin_bit_cast(float, wa[j] & 0xffff0000u);
    float blo = __builtin_bit_cast(float, wb[j] << 16);
    float bhi = __builtin_bit_cast(float, wb[j] & 0xffff0000u);
    float rlo = w1 * alo + w2 * blo;
    float rhi = w1 * ahi + w2 * bhi;
    out[j] = (u32)f2bf(rlo) | ((u32)f2bf(rhi) << 16);
  }
  uint4 ov = {out[0], out[1], out[2], out[3]};
  *(uint4*)&ctx[((size_t)(b * SEQ + q)) * D_MODEL + h * DK + d0] = ov;
}

// ---------------------------------------------------------------------------
// Kernel 6: output projection, fp32 out.  128x64 tile, BK=64, grid (32,16).
// Fully double-buffered single-barrier pipeline.
// ---------------------------------------------------------------------------
__global__ __launch_bounds__(256) void gemm_out(
    const u16* __restrict__ A, const u16* __restrict__ Bw,
    const float* __restrict__ bias, float* __restrict__ Cout) {
  __shared__ __align__(16) u16 sAb[2][128 * 64];
  __shared__ __align__(16) u16 sBc[2][64 * 64];

  const int t = threadIdx.x;
  const int m0 = blockIdx.x * 128, n0 = blockIdx.y * 64;  // XCD swizzle
  const int lane = t & 63, wv = t >> 6;
  const int wm = (wv >> 1) * 64, wn = (wv & 1) * 32;
  const int c = lane & 15, qd = lane >> 4;

  const int arow = t >> 3;
  const int aoff = (((t & 7) - arow) & 7) * 8;
  const u16* gaA = A + (size_t)(m0 + arow) * D_MODEL + aoff;
  const u16* gaB = Bw + (size_t)(n0 + arow) * D_MODEL + aoff;

  // prologue
#pragma unroll
  for (int j = 0; j < 4; ++j)
    gload16(gaA + (size_t)(32 * j) * D_MODEL, &sAb[0][(t + 256 * j) * 8]);
#pragma unroll
  for (int j = 0; j < 2; ++j)
    gload16(gaB + (size_t)(32 * j) * D_MODEL, &sBc[0][(t + 256 * j) * 8]);

  f32x4 acc[4][2] = {};

  for (int kbi = 0; kbi < 16; ++kbi) {
    const int cur = kbi & 1;
    __syncthreads();  // drains this iter's buffers (loads issued last iter)
    if (kbi + 1 < 16) {
      const int kb2 = (kbi + 1) * 64;
#pragma unroll
      for (int j = 0; j < 4; ++j)
        gload16(gaA + kb2 + (size_t)(32 * j) * D_MODEL,
                &sAb[1 - cur][(t + 256 * j) * 8]);
#pragma unroll
      for (int j = 0; j < 2; ++j)
        gload16(gaB + kb2 + (size_t)(32 * j) * D_MODEL,
                &sBc[1 - cur][(t + 256 * j) * 8]);
    }
    const u16* sA = sAb[cur];
    const u16* sB = sBc[cur];
#pragma unroll
    for (int s = 0; s < 2; ++s) {
      const int ao = ((s * 4 + qd + wm + c) & 7) * 8;
      const int bo = ((s * 4 + qd + wn + c) & 7) * 8;
      bf16x8 af[4], bfr[2];
#pragma unroll
      for (int i = 0; i < 4; ++i)
        af[i] = *(const bf16x8*)&sA[(wm + i * 16 + c) * 64 + ao];
#pragma unroll
      for (int j = 0; j < 2; ++j)
        bfr[j] = *(const bf16x8*)&sB[(wn + j * 16 + c) * 64 + bo];
#pragma unroll
      for (int i = 0; i < 4; ++i)
#pragma unroll
        for (int j = 0; j < 2; ++j)
          acc[i][j] = __builtin_amdgcn_mfma_f32_16x16x32_bf16(af[i], bfr[j],
                                                              acc[i][j], 0, 0, 0);
    }
  }

#pragma unroll
  for (int j = 0; j < 2; ++j) {
    const int col = n0 + wn + j * 16 + c;
    const float bv = bias[col];
#pragma unroll
    for (int i = 0; i < 4; ++i)
#pragma unroll
      for (int r = 0; r < 4; ++r) {
        const int row = m0 + wm + i * 16 + qd * 4 + r;
        Cout[(size_t)row * D_MODEL + col] = acc[i][j][r] + bv;
      }
  }
}

// ---------------------------------------------------------------------------
extern "C" void kernel_launch(void* const* d_in, const int* in_sizes, int n_in,
                              void* d_out, int out_size, void* d_ws,
                              size_t ws_size, hipStream_t stream) {
  const float* query = (const float*)d_in[0];
  const float* key   = (const float*)d_in[1];
  const float* value = (const float*)d_in[2];
  const int*   mask  = (const int*)d_in[3];
  const float* Wq = (const float*)d_in[4];
  const float* bq = (const float*)d_in[5];
  const float* Wk = (const float*)d_in[6];
  const float* bk = (const float*)d_in[7];
  const float* Wv = (const float*)d_in[8];
  const float* bv = (const float*)d_in[9];
  const float* Wo = (const float*)d_in[10];
  const float* bo = (const float*)d_in[11];

  // ws (u16 units, 32M = 64 MB):
  //   [0..4M)   VTc          [4M..12M)  Opart
  //   [12M..16M) Wb: Wq/Wk/Wv bf16 (dead after gemm_qkv; ml aliases Wq), Wo live
  //   [16M..28M) QKV: Q | K | VT(orig)   [28M..32M) CTX (idx/cnt alias early)
  u16* ws  = (u16*)d_ws;
  u16* Wb  = ws + ((size_t)12 << 20);
  u16* QKV = ws + ((size_t)16 << 20);
  u16* CTX = ws + ((size_t)28 << 20);
  u16* VTc = ws;
  u16* Opart = ws + ((size_t)4 << 20);
  float* ml = (float*)(ws + ((size_t)12 << 20));
  int* idxp = (int*)(ws + ((size_t)28 << 20));
  int* cntp = idxp + 2 * SEQ;

  prep<<<dim3(1026), dim3(256), 0, stream>>>(mask, Wq, Wk, Wv, Wo, Wb, idxp,
                                             cntp);
  gemm_qkv<<<dim3(32, 8, 3), dim3(256), 0, stream>>>(query, key, value, Wb, bq,
                                                     bk, bv, QKV);
  vtc_gather<<<dim3(2048), dim3(256), 0, stream>>>(QKV + ((size_t)8 << 20), idxp,
                                                   cntp, VTc);
  mha_attn<<<dim3(16, 16, 4), dim3(256), 0, stream>>>(QKV, VTc, idxp, cntp,
                                                      Opart, ml);
  mha_combine<<<dim3(2048), dim3(256), 0, stream>>>(Opart, ml, CTX);
  gemm_out<<<dim3(32, 16), dim3(256), 0, stream>>>(CTX, Wb + ((size_t)3 << 20),
                                                   bo, (float*)d_out);
}

// Round 13
// 217.923 us; speedup vs baseline: 1.2711x; 1.2711x over previous
//
#include <hip/hip_runtime.h>
#include <cstdint>
#include <cstddef>

typedef unsigned short u16;
typedef unsigned int   u32;
typedef __bf16 bf16x8 __attribute__((ext_vector_type(8)));
typedef float  f32x4  __attribute__((ext_vector_type(4)));

#define D_MODEL 1024
#define SEQ     2048
#define NTOK    4096   // B*S
#define NHEAD   16
#define DK      64

// hardware exp2 (v_exp_f32)
__device__ __forceinline__ float fast_exp2(float x) {
  return __builtin_amdgcn_exp2f(x);
}

// fp32 -> bf16 round-to-nearest-even
__device__ __forceinline__ u16 f2bf(float f) {
  u32 u = __builtin_bit_cast(u32, f);
  u += 0x7fffu + ((u >> 16) & 1u);
  return (u16)(u >> 16);
}

// async global->LDS, 16B per lane (dest must be wave-uniform base + lane*16)
__device__ __forceinline__ void gload16(const u16* g, u16* l) {
  __builtin_amdgcn_global_load_lds(
      (__attribute__((address_space(1))) void*)(uintptr_t)g,
      (__attribute__((address_space(3))) void*)l,
      16, 0, 0);
}

// ---------------------------------------------------------------------------
// Kernel 1: prep = mask scan + rank (blocks 0-1) + weight fp32->bf16 (rest).
// idx[b][j] = s of j-th live key; rank[b][s] = #live keys before s (compact
// position); cnt[b] = #live.  idx pads = 0.
// ---------------------------------------------------------------------------
__global__ __launch_bounds__(256) void prep(
    const int* __restrict__ mask, const float* __restrict__ wq,
    const float* __restrict__ wk, const float* __restrict__ wv,
    const float* __restrict__ wo, u16* __restrict__ wb,
    int* __restrict__ idx, int* __restrict__ rank, int* __restrict__ cnt) {
  const int t = threadIdx.x;
  if (blockIdx.x < 2) {
    const int b = blockIdx.x;
    const int lane = t & 63, w = t >> 6;
    __shared__ int sW[4];
    __shared__ int sTot;
    int m8[8];
    const int base = b * SEQ + t * 8;
    int tot = 0;
#pragma unroll
    for (int i = 0; i < 8; ++i) {
      m8[i] = (mask[base + i] != 0);
      tot += m8[i];
    }
    int v = tot;  // wave inclusive scan
#pragma unroll
    for (int d = 1; d < 64; d <<= 1) {
      int u = __shfl_up(v, d);
      if (lane >= d) v += u;
    }
    if (lane == 63) sW[w] = v;
    __syncthreads();
    if (t == 0) {
      int run = 0;
#pragma unroll
      for (int i = 0; i < 4; ++i) { int tmp = sW[i]; sW[i] = run; run += tmp; }
      sTot = run;
    }
    __syncthreads();
    int pos = v - tot + sW[w];  // exclusive prefix
#pragma unroll
    for (int i = 0; i < 8; ++i) {
      rank[b * SEQ + t * 8 + i] = pos;
      if (m8[i]) { idx[b * SEQ + pos] = t * 8 + i; ++pos; }
    }
    const int cn = sTot;
    if (t == 0) cnt[b] = cn;
    for (int j = cn + t; j < SEQ; j += 256) idx[b * SEQ + j] = 0;
  } else {
    // ---- weights fp32 -> bf16 (4 x 1M) ----
    const int total = 1 << 20;  // float4 chunks
    const int stride = (gridDim.x - 2) * 256;
    for (int cid = (blockIdx.x - 2) * 256 + t; cid < total; cid += stride) {
      int which = cid >> 18;
      int off = cid & ((1 << 18) - 1);
      const float* src =
          which == 0 ? wq : (which == 1 ? wk : (which == 2 ? wv : wo));
      u16* dst = wb + ((size_t)which << 20);
      float4 f = ((const float4*)src)[off];
      ushort4 u;
      u.x = f2bf(f.x); u.y = f2bf(f.y); u.z = f2bf(f.z); u.w = f2bf(f.w);
      ((ushort4*)dst)[off] = u;
    }
  }
}

// ---------------------------------------------------------------------------
// Kernel 2: QKV projections reading fp32 inputs DIRECTLY (conversion fused,
// staged through LDS -- the R11-proven structure; per-register A prefetch is
// compiler-hostile, see R12 post-mortem).  128x128 tile, BK=64, grid
// (mtile=32, ntile=8, z=3): flat%8 = mtile%8 -> XCD L2 reuse.
// A fp32 -> regs -> convert -> sA (single buf); B double-buffered gload16
// issued post-barrier.  Rotated B k-slots -> conflict-free ds_read_b128.
// z==0: Q scaled by 0.125*log2(e).
// z==2: V written DIRECTLY COMPACTED into VTc[b][h][d][rank[s]] (live s only;
//       pads stay poisoned -> annihilated by p=0 in attention).
// ---------------------------------------------------------------------------
__global__ __launch_bounds__(256, 3) void gemm_qkv(
    const float* __restrict__ Aq, const float* __restrict__ Ak,
    const float* __restrict__ Av, const u16* __restrict__ Bw,
    const float* __restrict__ b0, const float* __restrict__ b1,
    const float* __restrict__ b2, const int* __restrict__ mask,
    const int* __restrict__ rank, u16* __restrict__ Cout) {
  __shared__ __align__(16) u16 smem[3 * 128 * 64];  // sA | sB0 | sB1; epi: sC
  u16* sA = smem;

  const int t = threadIdx.x;
  const int z = blockIdx.z;
  const float* Ap = (z == 0) ? Aq : ((z == 1) ? Ak : Av);
  const u16* Bp = Bw + ((size_t)z << 20);
  const float* bias = (z == 0) ? b0 : ((z == 1) ? b1 : b2);
  const float scl = (z == 0) ? 0.18033688011f : 1.0f;

  const int m0 = blockIdx.x * 128, n0 = blockIdx.y * 128;  // XCD swizzle
  const int lane = t & 63, wv = t >> 6;
  const int wm = (wv >> 1) * 64, wn = (wv & 1) * 64;
  const int c = lane & 15, qd = lane >> 4;

  // staging: chunk cc = t + 256j -> row = t>>3 + 32j, phys slot t&7, source
  // k-slot rotated by row (32j = 0 mod 8 -> j-invariant)
  const int arow = t >> 3;
  const int aoff = (((t & 7) - arow) & 7) * 8;
  const float* gaA = Ap + (size_t)(m0 + arow) * D_MODEL + aoff;
  const u16* gaB = Bp + (size_t)(n0 + arow) * D_MODEL + aoff;

  float4 pa[4][2];
  // prologue: A(0) -> regs, B(0) -> sB0
#pragma unroll
  for (int j = 0; j < 4; ++j) {
    pa[j][0] = *(const float4*)(gaA + (size_t)(32 * j) * D_MODEL);
    pa[j][1] = *(const float4*)(gaA + (size_t)(32 * j) * D_MODEL + 4);
  }
#pragma unroll
  for (int j = 0; j < 4; ++j)
    gload16(gaB + (size_t)(32 * j) * D_MODEL, smem + 8192 + (t + 256 * j) * 8);

  f32x4 acc[4][4] = {};

  for (int kbi = 0; kbi < 16; ++kbi) {
    const int cur = kbi & 1;
    __syncthreads();  // (a) drains in-flight prefetches; protects sA rewrite
    // convert A regs -> sA
#pragma unroll
    for (int j = 0; j < 4; ++j) {
      u32 w[4];
#pragma unroll
      for (int h2 = 0; h2 < 2; ++h2) {
        float4 f = pa[j][h2];
        w[2 * h2] = (u32)f2bf(f.x) | ((u32)f2bf(f.y) << 16);
        w[2 * h2 + 1] = (u32)f2bf(f.z) | ((u32)f2bf(f.w) << 16);
      }
      uint4 v4 = {w[0], w[1], w[2], w[3]};
      *(uint4*)&sA[(t + 256 * j) * 8] = v4;
    }
    __syncthreads();  // (b) sA visible (lgkm-only drain; vmcnt already 0)
    // issue NEXT-iter loads now -- they fly through the MFMA phase
    if (kbi + 1 < 16) {
      const int kb2 = (kbi + 1) * 64;
      u16* sBn = smem + 8192 + (1 - cur) * 8192;
#pragma unroll
      for (int j = 0; j < 4; ++j)
        gload16(gaB + kb2 + (size_t)(32 * j) * D_MODEL, sBn + (t + 256 * j) * 8);
#pragma unroll
      for (int j = 0; j < 4; ++j) {
        pa[j][0] = *(const float4*)(gaA + kb2 + (size_t)(32 * j) * D_MODEL);
        pa[j][1] = *(const float4*)(gaA + kb2 + (size_t)(32 * j) * D_MODEL + 4);
      }
    }
    const u16* sB = smem + 8192 + cur * 8192;
#pragma unroll
    for (int s = 0; s < 2; ++s) {
      const int ao = ((s * 4 + qd + wm + c) & 7) * 8;  // rotated k-slot
      const int bo = ((s * 4 + qd + wn + c) & 7) * 8;
      bf16x8 af[4], bfr[4];
#pragma unroll
      for (int i = 0; i < 4; ++i)
        af[i] = *(const bf16x8*)&sA[(wm + i * 16 + c) * 64 + ao];
#pragma unroll
      for (int j = 0; j < 4; ++j)
        bfr[j] = *(const bf16x8*)&sB[(wn + j * 16 + c) * 64 + bo];
#pragma unroll
      for (int i = 0; i < 4; ++i)
#pragma unroll
        for (int j = 0; j < 4; ++j)
          acc[i][j] = __builtin_amdgcn_mfma_f32_16x16x32_bf16(af[i], bfr[j],
                                                              acc[i][j], 0, 0, 0);
    }
  }
  __syncthreads();  // last MFMA reads done before smem reuse as sC

  u16* sC = smem;  // stride 136
  if (z == 2) {
    // stage transposed: sC[col_local][row_local]
#pragma unroll
    for (int j = 0; j < 4; ++j) {
      const int col = wn + j * 16 + c;
      const float bv = bias[n0 + col];
#pragma unroll
      for (int i = 0; i < 4; ++i)
#pragma unroll
        for (int r = 0; r < 4; ++r)
          sC[col * 136 + wm + i * 16 + qd * 4 + r] = f2bf(acc[i][j][r] + bv);
    }
    __syncthreads();
    // compacted V^T [b][h][d][rank[s]] -- live s only
    u16* VTc = Cout + ((size_t)2 << 22);
    const int bb = m0 >> 11, s0 = m0 & 2047;
    const int sidx = (t & 15) * 8;
    const int sg = bb * SEQ + s0 + sidx;
#pragma unroll
    for (int outer = 0; outer < 8; ++outer) {
      const int vrow = outer * 16 + (t >> 4);
      const int col = n0 + vrow;
      const int hh = col >> 6, dd = col & 63;
      const u16* src = &sC[vrow * 136 + sidx];
      u16* dstrow = VTc + ((size_t)((bb * NHEAD + hh) * DK + dd)) * SEQ;
#pragma unroll
      for (int i = 0; i < 8; ++i)
        if (mask[sg + i] != 0) dstrow[rank[sg + i]] = src[i];
    }
  } else {
    // stage row-major: sC[row_local][col_local]
#pragma unroll
    for (int j = 0; j < 4; ++j) {
      const int col = wn + j * 16 + c;
      const float bv = bias[n0 + col];
#pragma unroll
      for (int i = 0; i < 4; ++i)
#pragma unroll
        for (int r = 0; r < 4; ++r)
          sC[(wm + i * 16 + qd * 4 + r) * 136 + col] =
              f2bf((acc[i][j][r] + bv) * scl);
    }
    __syncthreads();
    u16* outp = Cout + ((size_t)z << 22);
    const int cidx = (t & 15) * 8;
#pragma unroll
    for (int outer = 0; outer < 8; ++outer) {
      const int lrow = outer * 16 + (t >> 4);
      uint4 val = *(const uint4*)&sC[lrow * 136 + cidx];
      *(uint4*)&outp[(size_t)(m0 + lrow) * D_MODEL + n0 + cidx] = val;
    }
  }
}

// ---------------------------------------------------------------------------
// Kernel 3: flash attention over COMPACTED live keys.  S^T orientation,
// fixed-max softmax (m=16, exp2 domain).  Split-K x2, pipelined prefetch.
// K rows gathered via idx during staging; V^T read from compacted VTc.
// ---------------------------------------------------------------------------
__global__ __launch_bounds__(256) void mha_attn(
    const u16* __restrict__ QKVb, const int* __restrict__ idx,
    const int* __restrict__ cnt, u16* __restrict__ Opart,
    float* __restrict__ ml) {
  __shared__ __align__(16) u16 sK[64 * 72];
  __shared__ __align__(16) u16 sVt[64 * 72];   // [d][key]
  __shared__ __align__(16) u16 sP[128 * 72];   // [q][key] = P^T rows

  const int t = threadIdx.x, lane = t & 63, wq = t >> 6;
  const int c = lane & 15, qd = lane >> 4;
  const int qb = blockIdx.x, h = blockIdx.y;
  const int b = blockIdx.z & 1, ck = blockIdx.z >> 1;

  const int cn = cnt[b];
  const int nb = (cn + 63) >> 6;
  const int half = (nb + 1) >> 1;
  const int kstart = ck ? half : 0;
  const int kend = ck ? nb : half;

  const u16* Qg = QKVb;
  const u16* Kg = QKVb + ((size_t)4 << 20);
  const u16* VTch = QKVb + ((size_t)8 << 20) +
                    ((size_t)((b * NHEAD + h) * DK)) * SEQ;  // compacted [d][j]
  const int rowbase = b * SEQ;
  const int colbase = h * DK;

  // ---- Q B-fragments direct from global (lane n=q=c, k=qd*8+j) ----
  bf16x8 aq[2][2];
#pragma unroll
  for (int qt = 0; qt < 2; ++qt) {
    const u16* g = Qg +
                   (size_t)(rowbase + qb * 128 + wq * 32 + qt * 16 + c) * D_MODEL +
                   colbase + qd * 8;
    aq[qt][0] = *(const bf16x8*)g;
    aq[qt][1] = *(const bf16x8*)(g + 32);
  }

  float l[2] = {0.f, 0.f};
  f32x4 o[2][4] = {};
  const float MADD = -1.4426950e9f;  // NEG_INF * log2(e)
  const float MFIX = 16.0f;          // fixed softmax max (exp2 domain)

  const int r0s = t >> 2, offs = (t & 3) * 16;
  const u16* gvb = VTch + (size_t)r0s * SEQ + offs;
  const int* idxb = idx + b * SEQ + r0s;

  uint4 k0, k1, v0, v1;
  int sNext2 = 0;
  if (kstart < kend) {
    const int s0i = idxb[kstart * 64];
    const u16* gk = Kg + (size_t)(rowbase + s0i) * D_MODEL + colbase + offs;
    const u16* gv = gvb + kstart * 64;
    k0 = *(const uint4*)gk;
    k1 = *(const uint4*)(gk + 8);
    v0 = *(const uint4*)gv;
    v1 = *(const uint4*)(gv + 8);
    if (kstart + 1 < kend) sNext2 = idxb[(kstart + 1) * 64];
  }

  for (int kbi = kstart; kbi < kend; ++kbi) {
    __syncthreads();  // previous iteration's sK/sVt reads complete
    *(uint4*)&sK[r0s * 72 + offs] = k0;
    *(uint4*)&sK[r0s * 72 + offs + 8] = k1;
    *(uint4*)&sVt[r0s * 72 + offs] = v0;
    *(uint4*)&sVt[r0s * 72 + offs + 8] = v1;
    __syncthreads();
    // prefetch next: K via idx loaded a full iteration earlier
    if (kbi + 1 < kend) {
      const u16* gk = Kg + (size_t)(rowbase + sNext2) * D_MODEL + colbase + offs;
      const u16* gv = gvb + (kbi + 1) * 64;
      k0 = *(const uint4*)gk;
      k1 = *(const uint4*)(gk + 8);
      v0 = *(const uint4*)gv;
      v1 = *(const uint4*)(gv + 8);
    }
    if (kbi + 2 < kend) sNext2 = idxb[(kbi + 2) * 64];

    // ---- S^T = K Q^T (+ pad mask on last partial block) ----
    const bool full = ((kbi + 1) << 6) <= cn;
    f32x4 st[2][4];
#pragma unroll
    for (int tt = 0; tt < 4; ++tt) {
      bf16x8 ak0 = *(const bf16x8*)&sK[(tt * 16 + c) * 72 + qd * 8];
      bf16x8 ak1 = *(const bf16x8*)&sK[(tt * 16 + c) * 72 + qd * 8 + 32];
      f32x4 cin;
      if (full) {
        cin = f32x4{0.f, 0.f, 0.f, 0.f};
      } else {
        const int jb = (kbi << 6) + tt * 16 + qd * 4;
        cin = f32x4{jb + 0 < cn ? 0.f : MADD, jb + 1 < cn ? 0.f : MADD,
                    jb + 2 < cn ? 0.f : MADD, jb + 3 < cn ? 0.f : MADD};
      }
#pragma unroll
      for (int qt = 0; qt < 2; ++qt) {
        f32x4 a =
            __builtin_amdgcn_mfma_f32_16x16x32_bf16(ak0, aq[qt][0], cin, 0, 0, 0);
        a = __builtin_amdgcn_mfma_f32_16x16x32_bf16(ak1, aq[qt][1], a, 0, 0, 0);
        st[qt][tt] = a;
      }
    }

    // ---- softmax numerator: p = exp2(s - MFIX) ----
#pragma unroll
    for (int qt = 0; qt < 2; ++qt) {
      float sum = 0.f;
      const int prow = (wq * 32 + qt * 16 + c) * 72;
#pragma unroll
      for (int tt = 0; tt < 4; ++tt) {
        u32 pk[2];
#pragma unroll
        for (int pr = 0; pr < 2; ++pr) {
          u32 p0 = __builtin_bit_cast(u32, fast_exp2(st[qt][tt][2 * pr] - MFIX));
          u32 p1 =
              __builtin_bit_cast(u32, fast_exp2(st[qt][tt][2 * pr + 1] - MFIX));
          u32 hi1 = p1 & 0xffff0000u;
          pk[pr] = (p0 >> 16) | hi1;
          sum += __builtin_bit_cast(float, p0 & 0xffff0000u);
          sum += __builtin_bit_cast(float, hi1);
        }
        uint2 pv2 = {pk[0], pk[1]};
        *(uint2*)&sP[prow + tt * 16 + qd * 4] = pv2;  // ds_write_b64
      }
      l[qt] += sum;
    }

    // ---- O^T += V^T P^T ----
    bf16x8 bp[2][2];
#pragma unroll
    for (int qt = 0; qt < 2; ++qt) {
      const int prow = (wq * 32 + qt * 16 + c) * 72;
      bp[qt][0] = *(const bf16x8*)&sP[prow + qd * 8];
      bp[qt][1] = *(const bf16x8*)&sP[prow + qd * 8 + 32];
    }
#pragma unroll
    for (int dt = 0; dt < 4; ++dt) {
      bf16x8 av0 = *(const bf16x8*)&sVt[(dt * 16 + c) * 72 + qd * 8];
      bf16x8 av1 = *(const bf16x8*)&sVt[(dt * 16 + c) * 72 + qd * 8 + 32];
#pragma unroll
      for (int qt = 0; qt < 2; ++qt) {
        o[qt][dt] =
            __builtin_amdgcn_mfma_f32_16x16x32_bf16(av0, bp[qt][0], o[qt][dt], 0, 0, 0);
        o[qt][dt] =
            __builtin_amdgcn_mfma_f32_16x16x32_bf16(av1, bp[qt][1], o[qt][dt], 0, 0, 0);
      }
    }
  }

  // ---- epilogue ----
  const size_t obase =
      (size_t)ck * 4194304 + ((size_t)((b * NHEAD + h) * SEQ) + qb * 128) * 64;
  const int mlbase = ((ck * 2 + b) * NHEAD + h) * SEQ + qb * 128;
#pragma unroll
  for (int qt = 0; qt < 2; ++qt) {
    float ls = l[qt];
    ls += __shfl_xor(ls, 16);
    ls += __shfl_xor(ls, 32);
    const float inv = (ls != 0.f) ? 1.0f / ls : 0.f;
    const int q = wq * 32 + qt * 16 + c;
#pragma unroll
    for (int dt = 0; dt < 4; ++dt) {
      u32 lo = (u32)f2bf(o[qt][dt][0] * inv) |
               ((u32)f2bf(o[qt][dt][1] * inv) << 16);
      u32 hi = (u32)f2bf(o[qt][dt][2] * inv) |
               ((u32)f2bf(o[qt][dt][3] * inv) << 16);
      uint2 ov = {lo, hi};
      *(uint2*)&Opart[obase + (size_t)q * 64 + dt * 16 + qd * 4] = ov;
    }
    if (qd == 0) ml[mlbase + q] = ls;
  }
}

// ---------------------------------------------------------------------------
// Kernel 4: combine the two key-chunk partials -> ctx bf16
// ---------------------------------------------------------------------------
__global__ __launch_bounds__(256) void mha_combine(
    const u16* __restrict__ Opart, const float* __restrict__ ml,
    u16* __restrict__ ctx) {
  const int tid = blockIdx.x * 256 + threadIdx.x;  // 524288 = 65536 rows x 8
  const int row = tid >> 3, d0 = (tid & 7) * 8;
  const int b = row >> 15, h = (row >> 11) & 15, q = row & 2047;
  float l1 = ml[row];
  float l2 = ml[65536 + row];
  float inv = 1.0f / (l1 + l2);
  float w1 = l1 * inv, w2 = l2 * inv;
  const size_t o1 = (size_t)row * 64 + d0;
  uint4 pa = *(const uint4*)(Opart + o1);
  uint4 pb = *(const uint4*)(Opart + 4194304 + o1);
  u32 wa[4] = {pa.x, pa.y, pa.z, pa.w};
  u32 wb[4] = {pb.x, pb.y, pb.z, pb.w};
  u32 out[4];
#pragma unroll
  for (int j = 0; j < 4; ++j) {
    float alo = __builtin_bit_cast(float, wa[j] << 16);
    float ahi = __builtin_bit_cast(float, wa[j] & 0xffff0000u);
    float blo = __builtin_bit_cast(float, wb[j] << 16);
    float bhi = __builtin_bit_cast(float, wb[j] & 0xffff0000u);
    float rlo = w1 * alo + w2 * blo;
    float rhi = w1 * ahi + w2 * bhi;
    out[j] = (u32)f2bf(rlo) | ((u32)f2bf(rhi) << 16);
  }
  uint4 ov = {out[0], out[1], out[2], out[3]};
  *(uint4*)&ctx[((size_t)(b * SEQ + q)) * D_MODEL + h * DK + d0] = ov;
}

// ---------------------------------------------------------------------------
// Kernel 5: output projection, fp32 out.  128x64 tile, BK=64, grid (32,16).
// Fully double-buffered single-barrier pipeline.
// ---------------------------------------------------------------------------
__global__ __launch_bounds__(256) void gemm_out(
    const u16* __restrict__ A, const u16* __restrict__ Bw,
    const float* __restrict__ bias, float* __restrict__ Cout) {
  __shared__ __align__(16) u16 sAb[2][128 * 64];
  __shared__ __align__(16) u16 sBc[2][64 * 64];

  const int t = threadIdx.x;
  const int m0 = blockIdx.x * 128, n0 = blockIdx.y * 64;  // XCD swizzle
  const int lane = t & 63, wv = t >> 6;
  const int wm = (wv >> 1) * 64, wn = (wv & 1) * 32;
  const int c = lane & 15, qd = lane >> 4;

  const int arow = t >> 3;
  const int aoff = (((t & 7) - arow) & 7) * 8;
  const u16* gaA = A + (size_t)(m0 + arow) * D_MODEL + aoff;
  const u16* gaB = Bw + (size_t)(n0 + arow) * D_MODEL + aoff;

  // prologue
#pragma unroll
  for (int j = 0; j < 4; ++j)
    gload16(gaA + (size_t)(32 * j) * D_MODEL, &sAb[0][(t + 256 * j) * 8]);
#pragma unroll
  for (int j = 0; j < 2; ++j)
    gload16(gaB + (size_t)(32 * j) * D_MODEL, &sBc[0][(t + 256 * j) * 8]);

  f32x4 acc[4][2] = {};

  for (int kbi = 0; kbi < 16; ++kbi) {
    const int cur = kbi & 1;
    __syncthreads();  // drains this iter's buffers (loads issued last iter)
    if (kbi + 1 < 16) {
      const int kb2 = (kbi + 1) * 64;
#pragma unroll
      for (int j = 0; j < 4; ++j)
        gload16(gaA + kb2 + (size_t)(32 * j) * D_MODEL,
                &sAb[1 - cur][(t + 256 * j) * 8]);
#pragma unroll
      for (int j = 0; j < 2; ++j)
        gload16(gaB + kb2 + (size_t)(32 * j) * D_MODEL,
                &sBc[1 - cur][(t + 256 * j) * 8]);
    }
    const u16* sA = sAb[cur];
    const u16* sB = sBc[cur];
#pragma unroll
    for (int s = 0; s < 2; ++s) {
      const int ao = ((s * 4 + qd + wm + c) & 7) * 8;
      const int bo = ((s * 4 + qd + wn + c) & 7) * 8;
      bf16x8 af[4], bfr[2];
#pragma unroll
      for (int i = 0; i < 4; ++i)
        af[i] = *(const bf16x8*)&sA[(wm + i * 16 + c) * 64 + ao];
#pragma unroll
      for (int j = 0; j < 2; ++j)
        bfr[j] = *(const bf16x8*)&sB[(wn + j * 16 + c) * 64 + bo];
#pragma unroll
      for (int i = 0; i < 4; ++i)
#pragma unroll
        for (int j = 0; j < 2; ++j)
          acc[i][j] = __builtin_amdgcn_mfma_f32_16x16x32_bf16(af[i], bfr[j],
                                                              acc[i][j], 0, 0, 0);
    }
  }

#pragma unroll
  for (int j = 0; j < 2; ++j) {
    const int col = n0 + wn + j * 16 + c;
    const float bv = bias[col];
#pragma unroll
    for (int i = 0; i < 4; ++i)
#pragma unroll
      for (int r = 0; r < 4; ++r) {
        const int row = m0 + wm + i * 16 + qd * 4 + r;
        Cout[(size_t)row * D_MODEL + col] = acc[i][j][r] + bv;
      }
  }
}

// ---------------------------------------------------------------------------
extern "C" void kernel_launch(void* const* d_in, const int* in_sizes, int n_in,
                              void* d_out, int out_size, void* d_ws,
                              size_t ws_size, hipStream_t stream) {
  const float* query = (const float*)d_in[0];
  const float* key   = (const float*)d_in[1];
  const float* value = (const float*)d_in[2];
  const int*   mask  = (const int*)d_in[3];
  const float* Wq = (const float*)d_in[4];
  const float* bq = (const float*)d_in[5];
  const float* Wk = (const float*)d_in[6];
  const float* bk = (const float*)d_in[7];
  const float* Wv = (const float*)d_in[8];
  const float* bv = (const float*)d_in[9];
  const float* Wo = (const float*)d_in[10];
  const float* bo = (const float*)d_in[11];

  // ws (u16 units, 32M = 64 MB):
  //   [0..8M)   Opart (attn partials)   [8M..8.25M) ml
  //   [12M..16M) Wb weights bf16 (Wo at [15M..16M) live to end)
  //   [16M..28M) QKV: Q | K | VTc(compacted, written by gemm_qkv z==2)
  //   [28M..32M) CTX; idx/rank/cnt ints at its head (consumed by qkv/attn
  //              BEFORE combine overwrites CTX)
  u16* ws  = (u16*)d_ws;
  u16* Opart = ws;
  float* ml = (float*)(ws + ((size_t)8 << 20));
  u16* Wb  = ws + ((size_t)12 << 20);
  u16* QKV = ws + ((size_t)16 << 20);
  u16* CTX = ws + ((size_t)28 << 20);
  int* idxp = (int*)(ws + ((size_t)28 << 20));
  int* rankp = idxp + 2 * SEQ;
  int* cntp = rankp + 2 * SEQ;

  prep<<<dim3(1026), dim3(256), 0, stream>>>(mask, Wq, Wk, Wv, Wo, Wb, idxp,
                                             rankp, cntp);
  gemm_qkv<<<dim3(32, 8, 3), dim3(256), 0, stream>>>(query, key, value, Wb, bq,
                                                     bk, bv, mask, rankp, QKV);
  mha_attn<<<dim3(16, 16, 4), dim3(256), 0, stream>>>(QKV, idxp, cntp, Opart,
                                                      ml);
  mha_combine<<<dim3(2048), dim3(256), 0, stream>>>(Opart, ml, CTX);
  gemm_out<<<dim3(32, 16), dim3(256), 0, stream>>>(CTX, Wb + ((size_t)3 << 20),
                                                   bo, (float*)d_out);
}

// Round 14
// 215.438 us; speedup vs baseline: 1.2857x; 1.0115x over previous
//
#include <hip/hip_runtime.h>
#include <cstdint>
#include <cstddef>

typedef unsigned short u16;
typedef unsigned int   u32;
typedef __bf16 bf16x8 __attribute__((ext_vector_type(8)));
typedef float  f32x4  __attribute__((ext_vector_type(4)));

#define D_MODEL 1024
#define SEQ     2048
#define NTOK    4096   // B*S
#define NHEAD   16
#define DK      64

// hardware exp2 (v_exp_f32)
__device__ __forceinline__ float fast_exp2(float x) {
  return __builtin_amdgcn_exp2f(x);
}

// fp32 -> bf16 round-to-nearest-away (1 add vs RNE's 3 ops; same half-ulp bound)
__device__ __forceinline__ u16 f2bf(float f) {
  u32 u = __builtin_bit_cast(u32, f);
  return (u16)((u + 0x8000u) >> 16);
}

// async global->LDS, 16B per lane (dest must be wave-uniform base + lane*16)
__device__ __forceinline__ void gload16(const u16* g, u16* l) {
  __builtin_amdgcn_global_load_lds(
      (__attribute__((address_space(1))) void*)(uintptr_t)g,
      (__attribute__((address_space(3))) void*)l,
      16, 0, 0);
}

// ---------------------------------------------------------------------------
// Kernel 1: prep = mask scan (blocks 0-1) + weight fp32->bf16 (blocks 2..)
// ---------------------------------------------------------------------------
__global__ __launch_bounds__(256) void prep(
    const int* __restrict__ mask, const float* __restrict__ wq,
    const float* __restrict__ wk, const float* __restrict__ wv,
    const float* __restrict__ wo, u16* __restrict__ wb,
    int* __restrict__ idx, int* __restrict__ cnt) {
  const int t = threadIdx.x;
  if (blockIdx.x < 2) {
    const int b = blockIdx.x;
    const int lane = t & 63, w = t >> 6;
    __shared__ int sW[4];
    __shared__ int sTot;
    int m8[8];
    const int base = b * SEQ + t * 8;
    int tot = 0;
#pragma unroll
    for (int i = 0; i < 8; ++i) {
      m8[i] = (mask[base + i] != 0);
      tot += m8[i];
    }
    int v = tot;  // wave inclusive scan
#pragma unroll
    for (int d = 1; d < 64; d <<= 1) {
      int u = __shfl_up(v, d);
      if (lane >= d) v += u;
    }
    if (lane == 63) sW[w] = v;
    __syncthreads();
    if (t == 0) {
      int run = 0;
#pragma unroll
      for (int i = 0; i < 4; ++i) { int tmp = sW[i]; sW[i] = run; run += tmp; }
      sTot = run;
    }
    __syncthreads();
    int pos = v - tot + sW[w];
#pragma unroll
    for (int i = 0; i < 8; ++i)
      if (m8[i]) idx[b * SEQ + pos++] = t * 8 + i;
    const int cn = sTot;
    if (t == 0) cnt[b] = cn;
    for (int j = cn + t; j < SEQ; j += 256) idx[b * SEQ + j] = 0;
  } else {
    const int total = 1 << 20;  // float4 chunks
    const int stride = (gridDim.x - 2) * 256;
    for (int cid = (blockIdx.x - 2) * 256 + t; cid < total; cid += stride) {
      int which = cid >> 18;
      int off = cid & ((1 << 18) - 1);
      const float* src =
          which == 0 ? wq : (which == 1 ? wk : (which == 2 ? wv : wo));
      u16* dst = wb + ((size_t)which << 20);
      float4 f = ((const float4*)src)[off];
      ushort4 u;
      u.x = f2bf(f.x); u.y = f2bf(f.y); u.z = f2bf(f.z); u.w = f2bf(f.w);
      ((ushort4*)dst)[off] = u;
    }
  }
}

// ---------------------------------------------------------------------------
// Kernel 2: QKV projections reading fp32 inputs DIRECTLY (conversion fused,
// staged through LDS -- R11-proven structure).  128x128 tile, BK=64, grid
// (mtile=32, ntile=8, z=3): flat%8 = mtile%8 -> XCD L2 reuse.
// A fp32 -> regs -> convert -> sA; B double-buffered gload16 post-barrier.
// Rotated B k-slots -> conflict-free ds_read_b128.
// z==0: Q scaled by 0.125*log2(e).  z==2: V transposed [b][h][d][s].
// ---------------------------------------------------------------------------
__global__ __launch_bounds__(256, 3) void gemm_qkv(
    const float* __restrict__ Aq, const float* __restrict__ Ak,
    const float* __restrict__ Av, const u16* __restrict__ Bw,
    const float* __restrict__ b0, const float* __restrict__ b1,
    const float* __restrict__ b2, u16* __restrict__ Cout) {
  __shared__ __align__(16) u16 smem[3 * 128 * 64];  // sA | sB0 | sB1; epi: sC
  u16* sA = smem;

  const int t = threadIdx.x;
  const int z = blockIdx.z;
  const float* Ap = (z == 0) ? Aq : ((z == 1) ? Ak : Av);
  const u16* Bp = Bw + ((size_t)z << 20);
  const float* bias = (z == 0) ? b0 : ((z == 1) ? b1 : b2);
  const float scl = (z == 0) ? 0.18033688011f : 1.0f;

  const int m0 = blockIdx.x * 128, n0 = blockIdx.y * 128;  // XCD swizzle
  const int lane = t & 63, wv = t >> 6;
  const int wm = (wv >> 1) * 64, wn = (wv & 1) * 64;
  const int c = lane & 15, qd = lane >> 4;

  const int arow = t >> 3;
  const int aoff = (((t & 7) - arow) & 7) * 8;
  const float* gaA = Ap + (size_t)(m0 + arow) * D_MODEL + aoff;
  const u16* gaB = Bp + (size_t)(n0 + arow) * D_MODEL + aoff;

  float4 pa[4][2];
#pragma unroll
  for (int j = 0; j < 4; ++j) {
    pa[j][0] = *(const float4*)(gaA + (size_t)(32 * j) * D_MODEL);
    pa[j][1] = *(const float4*)(gaA + (size_t)(32 * j) * D_MODEL + 4);
  }
#pragma unroll
  for (int j = 0; j < 4; ++j)
    gload16(gaB + (size_t)(32 * j) * D_MODEL, smem + 8192 + (t + 256 * j) * 8);

  f32x4 acc[4][4] = {};

  for (int kbi = 0; kbi < 16; ++kbi) {
    const int cur = kbi & 1;
    __syncthreads();  // (a) drains in-flight prefetches; protects sA rewrite
#pragma unroll
    for (int j = 0; j < 4; ++j) {
      u32 w[4];
#pragma unroll
      for (int h2 = 0; h2 < 2; ++h2) {
        float4 f = pa[j][h2];
        w[2 * h2] = (u32)f2bf(f.x) | ((u32)f2bf(f.y) << 16);
        w[2 * h2 + 1] = (u32)f2bf(f.z) | ((u32)f2bf(f.w) << 16);
      }
      uint4 v4 = {w[0], w[1], w[2], w[3]};
      *(uint4*)&sA[(t + 256 * j) * 8] = v4;
    }
    __syncthreads();  // (b) sA visible
    if (kbi + 1 < 16) {
      const int kb2 = (kbi + 1) * 64;
      u16* sBn = smem + 8192 + (1 - cur) * 8192;
#pragma unroll
      for (int j = 0; j < 4; ++j)
        gload16(gaB + kb2 + (size_t)(32 * j) * D_MODEL, sBn + (t + 256 * j) * 8);
#pragma unroll
      for (int j = 0; j < 4; ++j) {
        pa[j][0] = *(const float4*)(gaA + kb2 + (size_t)(32 * j) * D_MODEL);
        pa[j][1] = *(const float4*)(gaA + kb2 + (size_t)(32 * j) * D_MODEL + 4);
      }
    }
    const u16* sB = smem + 8192 + cur * 8192;
#pragma unroll
    for (int s = 0; s < 2; ++s) {
      const int ao = ((s * 4 + qd + wm + c) & 7) * 8;
      const int bo = ((s * 4 + qd + wn + c) & 7) * 8;
      bf16x8 af[4], bfr[4];
#pragma unroll
      for (int i = 0; i < 4; ++i)
        af[i] = *(const bf16x8*)&sA[(wm + i * 16 + c) * 64 + ao];
#pragma unroll
      for (int j = 0; j < 4; ++j)
        bfr[j] = *(const bf16x8*)&sB[(wn + j * 16 + c) * 64 + bo];
#pragma unroll
      for (int i = 0; i < 4; ++i)
#pragma unroll
        for (int j = 0; j < 4; ++j)
          acc[i][j] = __builtin_amdgcn_mfma_f32_16x16x32_bf16(af[i], bfr[j],
                                                              acc[i][j], 0, 0, 0);
    }
  }
  __syncthreads();  // last MFMA reads done before smem reuse as sC

  u16* sC = smem;  // stride 136
  if (z == 2) {
#pragma unroll
    for (int j = 0; j < 4; ++j) {
      const int col = wn + j * 16 + c;
      const float bv = bias[n0 + col];
#pragma unroll
      for (int i = 0; i < 4; ++i)
#pragma unroll
        for (int r = 0; r < 4; ++r)
          sC[col * 136 + wm + i * 16 + qd * 4 + r] = f2bf(acc[i][j][r] + bv);
    }
    __syncthreads();
    u16* VT = Cout + ((size_t)2 << 22);
    const int bb = m0 >> 11, s0 = m0 & 2047;
    const int sidx = (t & 15) * 8;
#pragma unroll
    for (int outer = 0; outer < 8; ++outer) {
      const int vrow = outer * 16 + (t >> 4);
      const int col = n0 + vrow;
      const int hh = col >> 6, dd = col & 63;
      uint4 val = *(const uint4*)&sC[vrow * 136 + sidx];
      *(uint4*)&VT[((size_t)((bb * NHEAD + hh) * DK + dd)) * SEQ + s0 + sidx] =
          val;
    }
  } else {
#pragma unroll
    for (int j = 0; j < 4; ++j) {
      const int col = wn + j * 16 + c;
      const float bv = bias[n0 + col];
#pragma unroll
      for (int i = 0; i < 4; ++i)
#pragma unroll
        for (int r = 0; r < 4; ++r)
          sC[(wm + i * 16 + qd * 4 + r) * 136 + col] =
              f2bf((acc[i][j][r] + bv) * scl);
    }
    __syncthreads();
    u16* outp = Cout + ((size_t)z << 22);
    const int cidx = (t & 15) * 8;
#pragma unroll
    for (int outer = 0; outer < 8; ++outer) {
      const int lrow = outer * 16 + (t >> 4);
      uint4 val = *(const uint4*)&sC[lrow * 136 + cidx];
      *(uint4*)&outp[(size_t)(m0 + lrow) * D_MODEL + n0 + cidx] = val;
    }
  }
}

// ---------------------------------------------------------------------------
// Kernel 3: compact V^T along s: VTc[row][j] = VT[row][idx[b][j]], j<cnt[b].
// ---------------------------------------------------------------------------
__global__ __launch_bounds__(256) void vtc_gather(const u16* __restrict__ VT,
                                                  const int* __restrict__ idx,
                                                  const int* __restrict__ cnt,
                                                  u16* __restrict__ VTc) {
  const int row = blockIdx.x;  // (b*16+h)*64+d in [0,2048)
  const int b = row >> 10;
  const int cn = cnt[b];
  const u16* src = VT + (size_t)row * SEQ;
  u16* dst = VTc + (size_t)row * SEQ;
  const int* ib = idx + b * SEQ;
  for (int j = threadIdx.x; j < cn; j += 256) dst[j] = src[ib[j]];
}

// ---------------------------------------------------------------------------
// Kernel 4: flash attention over COMPACTED live keys.  S^T orientation,
// fixed-max softmax (m=16, exp2 domain).  Split-K x2, pipelined prefetch.
// ---------------------------------------------------------------------------
__global__ __launch_bounds__(256) void mha_attn(
    const u16* __restrict__ QKVb, const u16* __restrict__ VTc,
    const int* __restrict__ idx, const int* __restrict__ cnt,
    u16* __restrict__ Opart, float* __restrict__ ml) {
  __shared__ __align__(16) u16 sK[64 * 72];
  __shared__ __align__(16) u16 sVt[64 * 72];   // [d][key]
  __shared__ __align__(16) u16 sP[128 * 72];   // [q][key] = P^T rows

  const int t = threadIdx.x, lane = t & 63, wq = t >> 6;
  const int c = lane & 15, qd = lane >> 4;
  const int qb = blockIdx.x, h = blockIdx.y;
  const int b = blockIdx.z & 1, ck = blockIdx.z >> 1;

  const int cn = cnt[b];
  const int nb = (cn + 63) >> 6;
  const int half = (nb + 1) >> 1;
  const int kstart = ck ? half : 0;
  const int kend = ck ? nb : half;

  const u16* Qg = QKVb;
  const u16* Kg = QKVb + ((size_t)4 << 20);
  const u16* VTch = VTc + ((size_t)((b * NHEAD + h) * DK)) * SEQ;
  const int rowbase = b * SEQ;
  const int colbase = h * DK;

  bf16x8 aq[2][2];
#pragma unroll
  for (int qt = 0; qt < 2; ++qt) {
    const u16* g = Qg +
                   (size_t)(rowbase + qb * 128 + wq * 32 + qt * 16 + c) * D_MODEL +
                   colbase + qd * 8;
    aq[qt][0] = *(const bf16x8*)g;
    aq[qt][1] = *(const bf16x8*)(g + 32);
  }

  float l[2] = {0.f, 0.f};
  f32x4 o[2][4] = {};
  const float MADD = -1.4426950e9f;  // NEG_INF * log2(e)
  const float MFIX = 16.0f;          // fixed softmax max (exp2 domain)

  const int r0s = t >> 2, offs = (t & 3) * 16;
  const u16* gvb = VTch + (size_t)r0s * SEQ + offs;
  const int* idxb = idx + b * SEQ + r0s;

  uint4 k0, k1, v0, v1;
  int sNext2 = 0;
  if (kstart < kend) {
    const int s0i = idxb[kstart * 64];
    const u16* gk = Kg + (size_t)(rowbase + s0i) * D_MODEL + colbase + offs;
    const u16* gv = gvb + kstart * 64;
    k0 = *(const uint4*)gk;
    k1 = *(const uint4*)(gk + 8);
    v0 = *(const uint4*)gv;
    v1 = *(const uint4*)(gv + 8);
    if (kstart + 1 < kend) sNext2 = idxb[(kstart + 1) * 64];
  }

  for (int kbi = kstart; kbi < kend; ++kbi) {
    __syncthreads();
    *(uint4*)&sK[r0s * 72 + offs] = k0;
    *(uint4*)&sK[r0s * 72 + offs + 8] = k1;
    *(uint4*)&sVt[r0s * 72 + offs] = v0;
    *(uint4*)&sVt[r0s * 72 + offs + 8] = v1;
    __syncthreads();
    if (kbi + 1 < kend) {
      const u16* gk = Kg + (size_t)(rowbase + sNext2) * D_MODEL + colbase + offs;
      const u16* gv = gvb + (kbi + 1) * 64;
      k0 = *(const uint4*)gk;
      k1 = *(const uint4*)(gk + 8);
      v0 = *(const uint4*)gv;
      v1 = *(const uint4*)(gv + 8);
    }
    if (kbi + 2 < kend) sNext2 = idxb[(kbi + 2) * 64];

    const bool full = ((kbi + 1) << 6) <= cn;
    f32x4 st[2][4];
#pragma unroll
    for (int tt = 0; tt < 4; ++tt) {
      bf16x8 ak0 = *(const bf16x8*)&sK[(tt * 16 + c) * 72 + qd * 8];
      bf16x8 ak1 = *(const bf16x8*)&sK[(tt * 16 + c) * 72 + qd * 8 + 32];
      f32x4 cin;
      if (full) {
        cin = f32x4{0.f, 0.f, 0.f, 0.f};
      } else {
        const int jb = (kbi << 6) + tt * 16 + qd * 4;
        cin = f32x4{jb + 0 < cn ? 0.f : MADD, jb + 1 < cn ? 0.f : MADD,
                    jb + 2 < cn ? 0.f : MADD, jb + 3 < cn ? 0.f : MADD};
      }
#pragma unroll
      for (int qt = 0; qt < 2; ++qt) {
        f32x4 a =
            __builtin_amdgcn_mfma_f32_16x16x32_bf16(ak0, aq[qt][0], cin, 0, 0, 0);
        a = __builtin_amdgcn_mfma_f32_16x16x32_bf16(ak1, aq[qt][1], a, 0, 0, 0);
        st[qt][tt] = a;
      }
    }

#pragma unroll
    for (int qt = 0; qt < 2; ++qt) {
      float sum = 0.f;
      const int prow = (wq * 32 + qt * 16 + c) * 72;
#pragma unroll
      for (int tt = 0; tt < 4; ++tt) {
        u32 pk[2];
#pragma unroll
        for (int pr = 0; pr < 2; ++pr) {
          u32 p0 = __builtin_bit_cast(u32, fast_exp2(st[qt][tt][2 * pr] - MFIX));
          u32 p1 =
              __builtin_bit_cast(u32, fast_exp2(st[qt][tt][2 * pr + 1] - MFIX));
          u32 hi1 = p1 & 0xffff0000u;
          pk[pr] = (p0 >> 16) | hi1;
          sum += __builtin_bit_cast(float, p0 & 0xffff0000u);
          sum += __builtin_bit_cast(float, hi1);
        }
        uint2 pv2 = {pk[0], pk[1]};
        *(uint2*)&sP[prow + tt * 16 + qd * 4] = pv2;
      }
      l[qt] += sum;
    }

    bf16x8 bp[2][2];
#pragma unroll
    for (int qt = 0; qt < 2; ++qt) {
      const int prow = (wq * 32 + qt * 16 + c) * 72;
      bp[qt][0] = *(const bf16x8*)&sP[prow + qd * 8];
      bp[qt][1] = *(const bf16x8*)&sP[prow + qd * 8 + 32];
    }
#pragma unroll
    for (int dt = 0; dt < 4; ++dt) {
      bf16x8 av0 = *(const bf16x8*)&sVt[(dt * 16 + c) * 72 + qd * 8];
      bf16x8 av1 = *(const bf16x8*)&sVt[(dt * 16 + c) * 72 + qd * 8 + 32];
#pragma unroll
      for (int qt = 0; qt < 2; ++qt) {
        o[qt][dt] =
            __builtin_amdgcn_mfma_f32_16x16x32_bf16(av0, bp[qt][0], o[qt][dt], 0, 0, 0);
        o[qt][dt] =
            __builtin_amdgcn_mfma_f32_16x16x32_bf16(av1, bp[qt][1], o[qt][dt], 0, 0, 0);
      }
    }
  }

  const size_t obase =
      (size_t)ck * 4194304 + ((size_t)((b * NHEAD + h) * SEQ) + qb * 128) * 64;
  const int mlbase = ((ck * 2 + b) * NHEAD + h) * SEQ + qb * 128;
#pragma unroll
  for (int qt = 0; qt < 2; ++qt) {
    float ls = l[qt];
    ls += __shfl_xor(ls, 16);
    ls += __shfl_xor(ls, 32);
    const float inv = (ls != 0.f) ? 1.0f / ls : 0.f;
    const int q = wq * 32 + qt * 16 + c;
#pragma unroll
    for (int dt = 0; dt < 4; ++dt) {
      u32 lo = (u32)f2bf(o[qt][dt][0] * inv) |
               ((u32)f2bf(o[qt][dt][1] * inv) << 16);
      u32 hi = (u32)f2bf(o[qt][dt][2] * inv) |
               ((u32)f2bf(o[qt][dt][3] * inv) << 16);
      uint2 ov = {lo, hi};
      *(uint2*)&Opart[obase + (size_t)q * 64 + dt * 16 + qd * 4] = ov;
    }
    if (qd == 0) ml[mlbase + q] = ls;
  }
}

// ---------------------------------------------------------------------------
// Kernel 5: output projection with FUSED split-K combine.  A[token][k] where
// k-block kbi == head h; per A-chunk: read Opart halves + (l1,l2), combine
// (l1*a + l2*b)/(l1+l2) in-register, convert bf16 -> sA (R11-proven 2-barrier
// reg->LDS pipeline).  B (Wo) double-buffered gload16.  fp32 out.
// 128x64 tile, BK=64, grid (32,16): flat%8 = mtile%8 -> XCD A-reuse.
// ---------------------------------------------------------------------------
__global__ __launch_bounds__(256, 2) void gemm_out(
    const u16* __restrict__ Opart, const float* __restrict__ ml,
    const u16* __restrict__ Bw, const float* __restrict__ bias,
    float* __restrict__ Cout) {
  __shared__ __align__(16) u16 smem[2 * 64 * 64 + 128 * 64];  // sB0|sB1|sA

  const int t = threadIdx.x;
  const int m0 = blockIdx.x * 128, n0 = blockIdx.y * 64;  // XCD swizzle
  const int lane = t & 63, wv = t >> 6;
  const int wm = (wv >> 1) * 64, wn = (wv & 1) * 32;
  const int c = lane & 15, qd = lane >> 4;
  u16* sA = smem + 8192;

  const int arow = t >> 3;                       // local token row (+32j)
  const int aoff = (((t & 7) - arow) & 7) * 8;   // rotated k-slot (j-invariant)
  const int bb = m0 >> 11, s0 = m0 & 2047;
  // Opart chunk base for head kbi, chunk j: row2 = (bb*16+kbi)*2048 + s
  const int r2base = bb * NHEAD * SEQ + s0 + arow;  // + kbi*2048 + 32j

  const int brow = t >> 3;
  const int boff = (((t & 7) - brow) & 7) * 8;
  const u16* gaB = Bw + (size_t)(n0 + brow) * D_MODEL + boff;

  // prologue: A(0) = combine(head 0) -> regs, B(0) -> sB0
  uint4 po1[4], po2[4];
  float pl1[4], pl2[4];
#pragma unroll
  for (int j = 0; j < 4; ++j) {
    const int r2 = r2base + 32 * j;  // kbi = 0
    po1[j] = *(const uint4*)(Opart + (size_t)r2 * 64 + aoff);
    po2[j] = *(const uint4*)(Opart + 4194304 + (size_t)r2 * 64 + aoff);
    pl1[j] = ml[r2];
    pl2[j] = ml[r2 + 65536];
  }
#pragma unroll
  for (int j = 0; j < 2; ++j)
    gload16(gaB + (size_t)(32 * j) * D_MODEL, smem + (t + 256 * j) * 8);

  f32x4 acc[4][2] = {};

  for (int kbi = 0; kbi < 16; ++kbi) {
    const int cur = kbi & 1;
    __syncthreads();  // (a) drains prefetches; protects sA rewrite
    // combine + convert -> sA
#pragma unroll
    for (int j = 0; j < 4; ++j) {
      const float inv = 1.0f / (pl1[j] + pl2[j]);
      const float w1 = pl1[j] * inv, w2 = pl2[j] * inv;
      u32 a4[4] = {po1[j].x, po1[j].y, po1[j].z, po1[j].w};
      u32 b4[4] = {po2[j].x, po2[j].y, po2[j].z, po2[j].w};
      u32 wo[4];
#pragma unroll
      for (int p = 0; p < 4; ++p) {
        float alo = __builtin_bit_cast(float, a4[p] << 16);
        float ahi = __builtin_bit_cast(float, a4[p] & 0xffff0000u);
        float blo = __builtin_bit_cast(float, b4[p] << 16);
        float bhi = __builtin_bit_cast(float, b4[p] & 0xffff0000u);
        float rlo = w1 * alo + w2 * blo;
        float rhi = w1 * ahi + w2 * bhi;
        wo[p] = (u32)f2bf(rlo) | ((u32)f2bf(rhi) << 16);
      }
      uint4 v4 = {wo[0], wo[1], wo[2], wo[3]};
      *(uint4*)&sA[(t + 256 * j) * 8] = v4;
    }
    __syncthreads();  // (b) sA visible
    // issue next-iter loads now (fly through MFMA phase)
    if (kbi + 1 < 16) {
      const int kb2 = (kbi + 1) * 64;
      u16* sBn = smem + (1 - cur) * 8192 / 2;  // 64*64 = 4096 u16 per buffer
#pragma unroll
      for (int j = 0; j < 2; ++j)
        gload16(gaB + kb2 + (size_t)(32 * j) * D_MODEL,
                smem + (1 - cur) * 4096 + (t + 256 * j) * 8);
      (void)sBn;
#pragma unroll
      for (int j = 0; j < 4; ++j) {
        const int r2 = r2base + (kbi + 1) * SEQ + 32 * j;
        po1[j] = *(const uint4*)(Opart + (size_t)r2 * 64 + aoff);
        po2[j] = *(const uint4*)(Opart + 4194304 + (size_t)r2 * 64 + aoff);
        pl1[j] = ml[r2];
        pl2[j] = ml[r2 + 65536];
      }
    }
    const u16* sB = smem + cur * 4096;
#pragma unroll
    for (int s = 0; s < 2; ++s) {
      const int ao = ((s * 4 + qd + wm + c) & 7) * 8;
      const int bo = ((s * 4 + qd + wn + c) & 7) * 8;
      bf16x8 af[4], bfr[2];
#pragma unroll
      for (int i = 0; i < 4; ++i)
        af[i] = *(const bf16x8*)&sA[(wm + i * 16 + c) * 64 + ao];
#pragma unroll
      for (int j = 0; j < 2; ++j)
        bfr[j] = *(const bf16x8*)&sB[(wn + j * 16 + c) * 64 + bo];
#pragma unroll
      for (int i = 0; i < 4; ++i)
#pragma unroll
        for (int j = 0; j < 2; ++j)
          acc[i][j] = __builtin_amdgcn_mfma_f32_16x16x32_bf16(af[i], bfr[j],
                                                              acc[i][j], 0, 0, 0);
    }
  }

#pragma unroll
  for (int j = 0; j < 2; ++j) {
    const int col = n0 + wn + j * 16 + c;
    const float bv = bias[col];
#pragma unroll
    for (int i = 0; i < 4; ++i)
#pragma unroll
      for (int r = 0; r < 4; ++r) {
        const int row = m0 + wm + i * 16 + qd * 4 + r;
        Cout[(size_t)row * D_MODEL + col] = acc[i][j][r] + bv;
      }
  }
}

// ---------------------------------------------------------------------------
extern "C" void kernel_launch(void* const* d_in, const int* in_sizes, int n_in,
                              void* d_out, int out_size, void* d_ws,
                              size_t ws_size, hipStream_t stream) {
  const float* query = (const float*)d_in[0];
  const float* key   = (const float*)d_in[1];
  const float* value = (const float*)d_in[2];
  const int*   mask  = (const int*)d_in[3];
  const float* Wq = (const float*)d_in[4];
  const float* bq = (const float*)d_in[5];
  const float* Wk = (const float*)d_in[6];
  const float* bk = (const float*)d_in[7];
  const float* Wv = (const float*)d_in[8];
  const float* bv = (const float*)d_in[9];
  const float* Wo = (const float*)d_in[10];
  const float* bo = (const float*)d_in[11];

  // ws (u16 units, 32M = 64 MB):
  //   [0..4M)   VTc          [4M..12M)  Opart (attn partials)
  //   [12M..16M) Wb: ml aliases Wq-bf16 (dead after gemm_qkv); Wo live to end
  //   [16M..28M) QKV: Q | K | VT(orig)   [28M..) idx/cnt ints
  u16* ws  = (u16*)d_ws;
  u16* VTc = ws;
  u16* Opart = ws + ((size_t)4 << 20);
  u16* Wb  = ws + ((size_t)12 << 20);
  float* ml = (float*)(ws + ((size_t)12 << 20));
  u16* QKV = ws + ((size_t)16 << 20);
  int* idxp = (int*)(ws + ((size_t)28 << 20));
  int* cntp = idxp + 2 * SEQ;

  prep<<<dim3(1026), dim3(256), 0, stream>>>(mask, Wq, Wk, Wv, Wo, Wb, idxp,
                                             cntp);
  gemm_qkv<<<dim3(32, 8, 3), dim3(256), 0, stream>>>(query, key, value, Wb, bq,
                                                     bk, bv, QKV);
  vtc_gather<<<dim3(2048), dim3(256), 0, stream>>>(QKV + ((size_t)8 << 20), idxp,
                                                   cntp, VTc);
  mha_attn<<<dim3(16, 16, 4), dim3(256), 0, stream>>>(QKV, VTc, idxp, cntp,
                                                      Opart, ml);
  gemm_out<<<dim3(32, 16), dim3(256), 0, stream>>>(Opart, ml,
                                                   Wb + ((size_t)3 << 20), bo,
                                                   (float*)d_out);
}